// Round 13
// baseline (1009.014 us; speedup 1.0000x reference)
//
#include <hip/hip_runtime.h>
#include <math.h>

#define N_NODES   100000
#define N_EDGES   1600000
#define D         64
#define NEG_SLOPE 0.2f

// Degrees ~ Poisson(16); max over 100k nodes ~ 38. Cap loop at 56 (paranoia).
#define DEG_CAP 56

// ROUND-13: R11/R12 kernels, but build+agg FUSED with per-bucket flags
// (producer-consumer, NO global barrier) -> one fewer launch boundary
// (~25us measured gap each, R10 isolation). Build keeps its full 1024-thread
// parallelism; agg waves spin only on their own bucket's flag (relaxed load
// + s_sleep; single acquire fence on exit). Build blocks are blockIdx 0..255
// -> scheduled first; spin bounded -> fail-visible, never hang.
#define NBUCK  256
#define BUCK_N 391           // ceil(100000/256); max dst 99999 -> bucket 255
#define BCAP   8192          // bucket edge-region stride; mean 6250, +24 sigma
#define PK_SHIFT 9           // dst_local in 9 bits (391 < 512); src in bits 9..25
#define PK_MASK  0x1FFu
#define CHUNK 2048
#define PART_BLOCKS ((N_EDGES + CHUNK - 1) / CHUNK)      // 782

typedef __attribute__((ext_vector_type(8))) _Float16 half8;
typedef __attribute__((ext_vector_type(2))) _Float16 half2v;
typedef __attribute__((ext_vector_type(4))) float floatx4;
typedef __attribute__((ext_vector_type(4))) int   intx4;
typedef __attribute__((ext_vector_type(4))) unsigned short ushort4v;

// fp32 -> bf16 bits, round-to-nearest-even
__device__ __forceinline__ unsigned short bfbits(float x) {
    unsigned u = __float_as_uint(x);
    u += 0x7fffu + ((u >> 16) & 1u);
    return (unsigned short)(u >> 16);
}
__device__ __forceinline__ float blo(unsigned v) { return __uint_as_float(v << 16); }
__device__ __forceinline__ float bhi(unsigned v) { return __uint_as_float(v & 0xffff0000u); }
// fp32 -> fp16 bits (RTE)
__device__ __forceinline__ unsigned short h16(float x) {
    union { _Float16 h; unsigned short u; } c; c.h = (_Float16)x; return c.u;
}
__device__ __forceinline__ half2v u2h(unsigned v) {
    union { unsigned u; half2v h; } c; c.u = v; return c.h;
}
__device__ __forceinline__ float fdot2(unsigned a, half2v b, float c) {
#if __has_builtin(__builtin_amdgcn_fdot2)
    return __builtin_amdgcn_fdot2(u2h(a), b, c, false);
#else
    half2v ah = u2h(a);
    return c + (float)ah[0] * (float)b[0] + (float)ah[1] * (float)b[1];
#endif
}

__device__ __forceinline__ int flag_ld_relaxed(const int* p) {
#if __has_builtin(__hip_atomic_load)
    return __hip_atomic_load(p, __ATOMIC_RELAXED, __HIP_MEMORY_SCOPE_AGENT);
#else
    return *(volatile const int*)p;
#endif
}
__device__ __forceinline__ void flag_st_release(int* p, int v) {
#if __has_builtin(__hip_atomic_store)
    __hip_atomic_store(p, v, __ATOMIC_RELEASE, __HIP_MEMORY_SCOPE_AGENT);
#else
    __threadfence();
    *(volatile int*)p = v;
#endif
}
__device__ __forceinline__ void acq_fence() {
#if __has_builtin(__builtin_amdgcn_fence)
    __builtin_amdgcn_fence(__ATOMIC_ACQUIRE, "agent");
#else
    __threadfence();
#endif
}

// ---- K1 (fused): proj role (512 blocks, R11 transposed-MFMA, validated) +
// partition role (782 blocks, LDS counting sort). Verbatim R12 K1 except:
// pbuf/off16 live in ws (d_out is pure output now) and block 0 zeroes bflag.
#define WT_STRIDE 72            // fp16 elems; 144 B row stride (16B-aligned)
#define PROJ_BLOCKS 512
#define PROJ_WAVES  (PROJ_BLOCKS * 4)
#define FUSED_BLOCKS (PROJ_BLOCKS + PART_BLOCKS)         // 1294

__global__ __launch_bounds__(256, 2) void proj_part_k(
    const float* __restrict__ feat,
    const float* __restrict__ Wq, const float* __restrict__ bq,
    const float* __restrict__ Wk, const float* __restrict__ bk,
    const float* __restrict__ Wf, const float* __restrict__ bf,
    unsigned short* __restrict__ qh, unsigned short* __restrict__ kf,
    const int* __restrict__ src, const int* __restrict__ dst,
    unsigned* __restrict__ pbuf, unsigned short* __restrict__ off16,
    int* __restrict__ bflag) {

    const int bx  = blockIdx.x;
    const int tid = threadIdx.x;

    if (bx == 0) bflag[tid] = 0;   // 256 flags; visible to K2 via kernel boundary

    __shared__ int smi[3 * 64 * WT_STRIDE / 2];   // 27648 B, shared by both roles

    if (bx >= PROJ_BLOCKS) {
        // ---------------- PARTITION role (LDS counting sort) ----------------
        const int hid = bx - PROJ_BLOCKS;
        unsigned* ecache = (unsigned*)smi;        // [2048] staged sorted edges
        int*      lcnt   = smi + CHUNK;           // [256] bucket counts
        int*      lsum   = smi + CHUNK + NBUCK;   // [256] scan workspace

        lcnt[tid] = 0;                            // blockDim == NBUCK == 256
        __syncthreads();

        int bkt[8]; int rnk[8]; unsigned pk[8];
        #pragma unroll
        for (int j = 0; j < 8; j++) bkt[j] = -1;

        const int cbase = hid * CHUNK;
        #pragma unroll
        for (int g = 0; g < 2; g++) {
            int eb = cbase + (g * 256 + tid) * 4;        // N_EDGES % 4 == 0
            if (eb < N_EDGES) {
                intx4 d4 = __builtin_nontemporal_load((const intx4*)(dst + eb));
                intx4 s4 = __builtin_nontemporal_load((const intx4*)(src + eb));
                #pragma unroll
                for (int j = 0; j < 4; j++) {
                    int dd = (j == 0) ? d4.x : (j == 1) ? d4.y : (j == 2) ? d4.z : d4.w;
                    int ss = (j == 0) ? s4.x : (j == 1) ? s4.y : (j == 2) ? s4.z : s4.w;
                    int b  = dd / BUCK_N;
                    bkt[g * 4 + j] = b;
                    rnk[g * 4 + j] = atomicAdd(&lcnt[b], 1);   // LDS only
                    pk[g * 4 + j]  = ((unsigned)ss << PK_SHIFT)
                                   | (unsigned)(dd - b * BUCK_N);
                }
            }
        }
        __syncthreads();

        // Hillis-Steele inclusive scan of lcnt -> lsum
        int own = lcnt[tid];
        lsum[tid] = own;
        __syncthreads();
        #pragma unroll
        for (int d2 = 1; d2 < NBUCK; d2 <<= 1) {
            int t = (tid >= d2) ? lsum[tid - d2] : 0;
            __syncthreads();
            lsum[tid] += t;
            __syncthreads();
        }
        int excl = lsum[tid] - own;               // exclusive offset of bucket tid

        // coalesced 512B offset-row write
        off16[(size_t)hid * NBUCK + tid] = (unsigned short)excl;
        __syncthreads();
        lsum[tid] = excl;                         // publish exclusive offsets
        __syncthreads();

        // scatter into LDS staging (sorted by bucket)
        #pragma unroll
        for (int j = 0; j < 8; j++) {
            int b = bkt[j];
            if (b >= 0) ecache[lsum[b] + rnk[j]] = pk[j];
        }
        __syncthreads();

        // fully coalesced stream-out (total is deterministic per block)
        int total = N_EDGES - cbase; if (total > CHUNK) total = CHUNK;
        for (int i = tid; i < total; i += 256)
            pbuf[(size_t)hid * CHUNK + i] = ecache[i];
        return;
    }

    // ---------------- PROJ role (R11 transposed-output MFMA, validated) ----
    const int pid  = bx;
    unsigned short* wt = (unsigned short*)smi;

    const int lane = tid & 63;
    const int wave = tid >> 6;
    const int m    = lane & 15;
    const int quad = lane >> 4;

    // stage W^T into LDS as fp16: wt[w][n][k]
    for (int idx = tid; idx < 64 * 64; idx += 256) {
        int i = idx >> 6, dd = idx & 63;                 // i = k-dim, dd = out-dim
        int o = dd * WT_STRIDE + i;
        wt[0 * 64 * WT_STRIDE + o] = h16(Wq[idx]);
        wt[1 * 64 * WT_STRIDE + o] = h16(Wk[idx]);
        wt[2 * 64 * WT_STRIDE + o] = h16(Wf[idx]);
    }
    __syncthreads();

    half8 Bf[3][4][2];
    floatx4 bias4[3][4];
    #pragma unroll
    for (int w = 0; w < 3; w++)
        #pragma unroll
        for (int nt = 0; nt < 4; nt++) {
            int n = nt * 16 + m;
            #pragma unroll
            for (int ks = 0; ks < 2; ks++)
                Bf[w][nt][ks] = *(const half8*)&wt[(w * 64 + n) * WT_STRIDE + ks * 32 + quad * 8];
        }
    #pragma unroll
    for (int nt = 0; nt < 4; nt++) {
        int dim0 = nt * 16 + quad * 4;      // this lane's 4 output dims
        bias4[0][nt] = *(const floatx4*)(bq + dim0);
        bias4[1][nt] = *(const floatx4*)(bk + dim0);
        bias4[2][nt] = *(const floatx4*)(bf + dim0);
    }

    const int NT  = N_NODES / 16;          // 6250 exact
    const int wid = pid * 4 + wave;

    for (int t = wid; t < NT; t += PROJ_WAVES) {
        int t0  = t * 16;
        int row = t0 + m;

        const floatx4* fr = (const floatx4*)(feat + (size_t)row * D + quad * 8);
        floatx4 x0 = __builtin_nontemporal_load(fr);
        floatx4 x1 = __builtin_nontemporal_load(fr + 1);
        floatx4 x2 = __builtin_nontemporal_load(fr + 8);
        floatx4 x3 = __builtin_nontemporal_load(fr + 9);

        half8 a0, a1;
        a0[0] = (_Float16)x0.x; a0[1] = (_Float16)x0.y;
        a0[2] = (_Float16)x0.z; a0[3] = (_Float16)x0.w;
        a0[4] = (_Float16)x1.x; a0[5] = (_Float16)x1.y;
        a0[6] = (_Float16)x1.z; a0[7] = (_Float16)x1.w;
        a1[0] = (_Float16)x2.x; a1[1] = (_Float16)x2.y;
        a1[2] = (_Float16)x2.z; a1[3] = (_Float16)x2.w;
        a1[4] = (_Float16)x3.x; a1[5] = (_Float16)x3.y;
        a1[6] = (_Float16)x3.z; a1[7] = (_Float16)x3.w;

        // SWAPPED operands: D = C^T tile; lane holds 4 consecutive dims of ONE node.
        floatx4 acc[3][4];
        #pragma unroll
        for (int w = 0; w < 3; w++)
            #pragma unroll
            for (int nt = 0; nt < 4; nt++) {
                floatx4 c = bias4[w][nt];
                c = __builtin_amdgcn_mfma_f32_16x16x32_f16(Bf[w][nt][0], a0, c, 0, 0, 0);
                c = __builtin_amdgcn_mfma_f32_16x16x32_f16(Bf[w][nt][1], a1, c, 0, 0, 0);
                acc[w][nt] = c;
            }

        int node = t0 + m;
        #pragma unroll
        for (int nt = 0; nt < 4; nt++) {
            int dim0 = nt * 16 + quad * 4;
            ushort4v vq, vk, vf;
            #pragma unroll
            for (int r = 0; r < 4; r++) {
                vq[r] = h16(acc[0][nt][r]);
                vk[r] = h16(acc[1][nt][r]);
                vf[r] = bfbits(acc[2][nt][r]);
            }
            *(ushort4v*)(qh + (size_t)node * D + dim0)        = vq;
            *(ushort4v*)(kf + (size_t)node * 128 + dim0)      = vk;
            *(ushort4v*)(kf + (size_t)node * 128 + 64 + dim0) = vf;
        }
    }
}

// ---- K2 (fused): build role (blocks 0..255, R12 dense-CSR build, 1024 thr,
// release-flag on completion) + agg role (blocks 256.., 16 nodes/block,
// spin on own bucket's flag then R12 agg body verbatim).
#define AGG_BLOCKS ((N_NODES + 15) / 16)                 // 6250
#define K2_BLOCKS  (NBUCK + AGG_BLOCKS)                  // 6506

__global__ __launch_bounds__(1024) void build_agg_k(
    const unsigned short* __restrict__ off16, const unsigned* __restrict__ pbuf,
    unsigned* __restrict__ edgelist, unsigned* __restrict__ offdeg,
    int* __restrict__ bflag,
    const unsigned short* __restrict__ qh, const unsigned short* __restrict__ kf,
    float* __restrict__ out) {

    const int bx  = blockIdx.x;
    const int tid = threadIdx.x;

    __shared__ int cnt[BUCK_N];
    __shared__ int scan[512];
    __shared__ int cur[BUCK_N];

    if (bx < NBUCK) {
        // ================= BUILD role (R12, verbatim) =================
        const int b = bx;
        for (int i = tid; i < BUCK_N; i += 1024) cnt[i] = 0;
        __syncthreads();

        int o0 = 0, o1 = 0;
        if (tid < PART_BLOCKS) {
            o0 = off16[(size_t)tid * NBUCK + b];
            if (b < NBUCK - 1) {
                o1 = off16[(size_t)tid * NBUCK + b + 1];
            } else {
                o1 = N_EDGES - tid * CHUNK; if (o1 > CHUNK) o1 = CHUNK;
            }
        }
        const unsigned* pp = pbuf + (size_t)tid * CHUNK;

        // pass 1: count
        for (int r = o0; r < o1; r++)
            atomicAdd(&cnt[pp[r] & PK_MASK], 1);
        __syncthreads();

        // scan 391 counters (padded to 512)
        if (tid < 512) scan[tid] = (tid < BUCK_N) ? cnt[tid] : 0;
        __syncthreads();
        #pragma unroll
        for (int d2 = 1; d2 < 512; d2 <<= 1) {
            int t = 0;
            if (tid < 512 && tid >= d2) t = scan[tid - d2];
            __syncthreads();
            if (tid < 512) scan[tid] += t;
            __syncthreads();
        }

        // publish bases + offdeg
        const int gbase = b * BUCK_N;
        const int ebase = b * BCAP;
        for (int i = tid; i < BUCK_N; i += 1024) {
            int excl = scan[i] - cnt[i];
            int base = ebase + excl;
            cur[i] = base;
            int node = gbase + i;
            if (node < N_NODES)
                offdeg[node] = (unsigned)base | ((unsigned)cnt[i] << 25);
        }
        __syncthreads();

        // pass 2: place (dense; within-node order arbitrary, softmax-invariant)
        for (int r = o0; r < o1; r++) {
            unsigned p = pp[r];
            int loc = (int)(p & PK_MASK);
            int idx = atomicAdd(&cur[loc], 1);    // LDS only
            edgelist[idx] = (p >> PK_SHIFT) << 8; // kf byte offset = src*256
        }
        __syncthreads();
        __threadfence();                           // block's writes -> visible
        if (tid == 0) flag_st_release(&bflag[b], 1);
        return;
    }

    // ================= AGG role (R12 body + flag spin) =================
    int wave = tid >> 6;
    int lane = tid & 63;
    int n    = (bx - NBUCK) * 16 + wave;
    if (n >= N_NODES) return;

    const int l8 = lane & 7;      // dim group: dims l8*8 .. l8*8+7
    const int eg = lane >> 3;     // edge slot: 0..7
    const int bkt = n / BUCK_N;   // this wave's producer bucket

    // bounded spin, relaxed loads (no per-iter cache inv); one acquire after
    int spins = 0;
    while (flag_ld_relaxed(&bflag[bkt]) == 0) {
        if (++spins > (1 << 20)) break;            // fail-visible, never hang
#if __has_builtin(__builtin_amdgcn_s_sleep)
        __builtin_amdgcn_s_sleep(1);
#endif
    }
    acq_fence();

    unsigned meta = offdeg[n];                    // broadcast (wave-uniform)
    int off_e = (int)(meta & 0x01FFFFFFu);
    int deg   = (int)(meta >> 25);
    if (deg > DEG_CAP) deg = DEG_CAP;             // paranoia; never hit

    int offs_all = (int)edgelist[off_e + lane];
    uint4 uq = *(const uint4*)(qh + (size_t)n * D + l8 * 8);
    half2v qp0 = u2h(uq.x), qp1 = u2h(uq.y), qp2 = u2h(uq.z), qp3 = u2h(uq.w);

    const char* kfb = (const char*)kf;

    float acc[8] = {0, 0, 0, 0, 0, 0, 0, 0};
    float l = 0.0f;   // 8x over-counted (all 8 l8-lanes add the same ez)

    bool v   = eg < deg;
    int  off = __shfl(offs_all, eg);
    off = v ? off : 0;
    uint4 ku = *(const uint4*)(kfb + off + l8 * 16);
    uint4 fu = *(const uint4*)(kfb + off + 128 + l8 * 16);

    for (int i0 = 0; i0 < deg; i0 += 8) {
        bool hasnext = (i0 + 8) < deg;       // wave-uniform
        int  i2  = i0 + 8 + eg;              // <= 63 always (i0 <= 48): valid lane
        bool v2  = i2 < deg;
        int  off2 = __shfl(offs_all, i2);    // unconditional: all lanes active
        off2 = v2 ? off2 : 0;
        uint4 kn = ku, fn = fu;
        if (hasnext) {
            kn = *(const uint4*)(kfb + off2 + l8 * 16);
            fn = *(const uint4*)(kfb + off2 + 128 + l8 * 16);
        }

        float dot = 0.0f;
        dot = fdot2(ku.x, qp0, dot);
        dot = fdot2(ku.y, qp1, dot);
        dot = fdot2(ku.z, qp2, dot);
        dot = fdot2(ku.w, qp3, dot);
        dot += __shfl_xor(dot, 1);
        dot += __shfl_xor(dot, 2);
        dot += __shfl_xor(dot, 4);          // all 8 lanes now hold the full dot

        float e  = dot > 0.0f ? dot : NEG_SLOPE * dot;
        e = fminf(e, 85.0f);
        float ez = v ? __expf(e) : 0.0f;
        l += ez;

        acc[0] = fmaf(ez, blo(fu.x), acc[0]);
        acc[1] = fmaf(ez, bhi(fu.x), acc[1]);
        acc[2] = fmaf(ez, blo(fu.y), acc[2]);
        acc[3] = fmaf(ez, bhi(fu.y), acc[3]);
        acc[4] = fmaf(ez, blo(fu.z), acc[4]);
        acc[5] = fmaf(ez, bhi(fu.z), acc[5]);
        acc[6] = fmaf(ez, blo(fu.w), acc[6]);
        acc[7] = fmaf(ez, bhi(fu.w), acc[7]);

        ku = kn; fu = fn; v = v2;
    }

    // reduce acc over the 8 edge slots (lanes differing in bits 3..5)
    #pragma unroll
    for (int d2 = 8; d2 < 64; d2 <<= 1) {
        #pragma unroll
        for (int j = 0; j < 8; j++) acc[j] += __shfl_xor(acc[j], d2);
    }
    // total l over all 64 lanes (8x the true denom -> inv = 8/l, exact scale)
    #pragma unroll
    for (int d2 = 1; d2 < 64; d2 <<= 1) l += __shfl_xor(l, d2);

    float inv = (deg > 0) ? 8.0f / fmaxf(l, 1e-30f) : 0.0f;
    if (eg == 0) {
        floatx4 o0 = {acc[0] * inv, acc[1] * inv, acc[2] * inv, acc[3] * inv};
        floatx4 o1 = {acc[4] * inv, acc[5] * inv, acc[6] * inv, acc[7] * inv};
        floatx4* op = (floatx4*)(out + (size_t)n * D + l8 * 8);
        __builtin_nontemporal_store(o0, op);
        __builtin_nontemporal_store(o1, op + 1);
    }
}

extern "C" void kernel_launch(void* const* d_in, const int* in_sizes, int n_in,
                              void* d_out, int out_size, void* d_ws, size_t ws_size,
                              hipStream_t stream) {
    const float* feat = (const float*)d_in[0];
    const int*   src  = (const int*)d_in[1];
    const int*   dst  = (const int*)d_in[2];
    const float* Wq   = (const float*)d_in[3];
    const float* bq   = (const float*)d_in[4];
    const float* Wk   = (const float*)d_in[5];
    const float* bk   = (const float*)d_in[6];
    const float* Wf   = (const float*)d_in[7];
    const float* bf   = (const float*)d_in[8];
    float* out = (float*)d_out;

    // workspace (54.0 MB < proven 64.4 MB), d_out is now PURE output:
    // qh 12.8 | kf 25.6 | edgelist 8.39 | offdeg 0.4 | pbuf 6.41 | off16 0.40
    // | bflag 1KB. All consumed state fully rewritten every launch; bflag
    // zeroed by K1 -> re-entrant across graph replays. No memsets.
    unsigned short* qh       = (unsigned short*)d_ws;
    unsigned short* kf       = qh + (size_t)N_NODES * D;
    unsigned*       edgelist = (unsigned*)(kf + (size_t)N_NODES * 2 * D);
    unsigned*       offdeg   = edgelist + (size_t)NBUCK * BCAP;
    unsigned*       pbuf     = offdeg + N_NODES;
    unsigned short* off16    = (unsigned short*)(pbuf + (size_t)PART_BLOCKS * CHUNK);
    int*            bflag    = (int*)(off16 + (size_t)PART_BLOCKS * NBUCK);

    proj_part_k<<<FUSED_BLOCKS, 256, 0, stream>>>(
        feat, Wq, bq, Wk, bk, Wf, bf, qh, kf, src, dst, pbuf, off16, bflag);

    build_agg_k<<<K2_BLOCKS, 1024, 0, stream>>>(
        off16, pbuf, edgelist, offdeg, bflag, qh, kf, out);
}

// Round 14
// 200.338 us; speedup vs baseline: 5.0366x; 5.0366x over previous
//
#include <hip/hip_runtime.h>
#include <math.h>

#define N_NODES   100000
#define N_EDGES   1600000
#define D         64
#define NEG_SLOPE 0.2f

// padded CSR: fixed slots per node. Degrees ~ Poisson(16); max over 100k
// nodes ~ 38. P(deg >= 56) ~ 1e-15 -> never hit with this fixed input set.
#define SLOTS 56
#define ROW   64             // srcperm row stride (ints): 256B rows, lane-aligned

// R14 = exact revert to ROUND-9 (best measured: 201.1us). Partition via
// per-block LDS counting sort -> ALL global writes coalesced. Zero global
// atomics, zero scattered stores, zero memsets in the whole pre-pass.
// R10 (global-barrier fusion, +140us) and R13 (flag-spin fusion, +800us)
// proved the launch-boundary cost is NOT recoverable in-kernel on MI355X.
#define NBUCK  256
#define BUCK_N 391           // ceil(100000/256); max dst 99999 -> bucket 255
#define PK_SHIFT 9           // dst_local in 9 bits (391 < 512); src in bits 9..25
#define PK_MASK  0x1FFu
#define CHUNK 2048
#define PART_BLOCKS ((N_EDGES + CHUNK - 1) / CHUNK)      // 782

typedef __attribute__((ext_vector_type(8))) _Float16 half8;
typedef __attribute__((ext_vector_type(2))) _Float16 half2v;
typedef __attribute__((ext_vector_type(4))) float floatx4;
typedef __attribute__((ext_vector_type(4))) int   intx4;

// fp32 -> bf16 bits, round-to-nearest-even
__device__ __forceinline__ unsigned short bfbits(float x) {
    unsigned u = __float_as_uint(x);
    u += 0x7fffu + ((u >> 16) & 1u);
    return (unsigned short)(u >> 16);
}
__device__ __forceinline__ float blo(unsigned v) { return __uint_as_float(v << 16); }
__device__ __forceinline__ float bhi(unsigned v) { return __uint_as_float(v & 0xffff0000u); }
// fp32 -> fp16 bits (RTE)
__device__ __forceinline__ unsigned short h16(float x) {
    union { _Float16 h; unsigned short u; } c; c.h = (_Float16)x; return c.u;
}
__device__ __forceinline__ half2v u2h(unsigned v) {
    union { unsigned u; half2v h; } c; c.u = v; return c.h;
}
__device__ __forceinline__ float fdot2(unsigned a, half2v b, float c) {
#if __has_builtin(__builtin_amdgcn_fdot2)
    return __builtin_amdgcn_fdot2(u2h(a), b, c, false);
#else
    half2v ah = u2h(a);
    return c + (float)ah[0] * (float)b[0] + (float)ah[1] * (float)b[1];
#endif
}

// ---- K1 (fused): proj role (512 blocks) + partition role (782 blocks,
// LDS counting sort; coalesced-only global writes).
#define WT_STRIDE 72            // fp16 elems; 144 B row stride (16B-aligned)
#define PROJ_BLOCKS 512
#define PROJ_WAVES  (PROJ_BLOCKS * 4)
#define FUSED_BLOCKS (PROJ_BLOCKS + PART_BLOCKS)         // 1294

__global__ __launch_bounds__(256, 2) void proj_part_k(
    const float* __restrict__ feat,
    const float* __restrict__ Wq, const float* __restrict__ bq,
    const float* __restrict__ Wk, const float* __restrict__ bk,
    const float* __restrict__ Wf, const float* __restrict__ bf,
    unsigned short* __restrict__ qh, unsigned short* __restrict__ kf,
    const int* __restrict__ src, const int* __restrict__ dst,
    unsigned* __restrict__ pbuf, unsigned short* __restrict__ off16) {

    const int bx  = blockIdx.x;
    const int tid = threadIdx.x;

    __shared__ int smi[3 * 64 * WT_STRIDE / 2];   // 27648 B, shared by both roles

    if (bx >= PROJ_BLOCKS) {
        // ---------------- PARTITION role (LDS counting sort) ----------------
        const int hid = bx - PROJ_BLOCKS;
        unsigned* ecache = (unsigned*)smi;        // [2048] staged sorted edges
        int*      lcnt   = smi + CHUNK;           // [256] bucket counts
        int*      lsum   = smi + CHUNK + NBUCK;   // [256] scan workspace

        lcnt[tid] = 0;                            // blockDim == NBUCK == 256
        __syncthreads();

        int bkt[8]; int rnk[8]; unsigned pk[8];
        #pragma unroll
        for (int j = 0; j < 8; j++) bkt[j] = -1;

        const int cbase = hid * CHUNK;
        #pragma unroll
        for (int g = 0; g < 2; g++) {
            int eb = cbase + (g * 256 + tid) * 4;        // N_EDGES % 4 == 0
            if (eb < N_EDGES) {
                intx4 d4 = __builtin_nontemporal_load((const intx4*)(dst + eb));
                intx4 s4 = __builtin_nontemporal_load((const intx4*)(src + eb));
                #pragma unroll
                for (int j = 0; j < 4; j++) {
                    int dd = (j == 0) ? d4.x : (j == 1) ? d4.y : (j == 2) ? d4.z : d4.w;
                    int ss = (j == 0) ? s4.x : (j == 1) ? s4.y : (j == 2) ? s4.z : s4.w;
                    int b  = dd / BUCK_N;
                    bkt[g * 4 + j] = b;
                    rnk[g * 4 + j] = atomicAdd(&lcnt[b], 1);   // LDS only
                    pk[g * 4 + j]  = ((unsigned)ss << PK_SHIFT)
                                   | (unsigned)(dd - b * BUCK_N);
                }
            }
        }
        __syncthreads();

        // Hillis-Steele inclusive scan of lcnt -> lsum
        int own = lcnt[tid];
        lsum[tid] = own;
        __syncthreads();
        #pragma unroll
        for (int d2 = 1; d2 < NBUCK; d2 <<= 1) {
            int t = (tid >= d2) ? lsum[tid - d2] : 0;
            __syncthreads();
            lsum[tid] += t;
            __syncthreads();
        }
        int excl = lsum[tid] - own;               // exclusive offset of bucket tid

        // coalesced 512B offset-row write
        off16[(size_t)hid * NBUCK + tid] = (unsigned short)excl;
        __syncthreads();
        lsum[tid] = excl;                         // publish exclusive offsets
        __syncthreads();

        // scatter into LDS staging (sorted by bucket)
        #pragma unroll
        for (int j = 0; j < 8; j++) {
            int b = bkt[j];
            if (b >= 0) ecache[lsum[b] + rnk[j]] = pk[j];
        }
        __syncthreads();

        // fully coalesced stream-out (total is deterministic per block)
        int total = N_EDGES - cbase; if (total > CHUNK) total = CHUNK;
        for (int i = tid; i < total; i += 256)
            pbuf[(size_t)hid * CHUNK + i] = ecache[i];
        return;
    }

    // ---------------- PROJ role (verbatim passing R8/R9) ----------------
    const int pid  = bx;
    unsigned short* wt = (unsigned short*)smi;

    const int lane = tid & 63;
    const int wave = tid >> 6;
    const int m    = lane & 15;
    const int quad = lane >> 4;

    // stage W^T into LDS as fp16: wt[w][n][k]
    for (int idx = tid; idx < 64 * 64; idx += 256) {
        int i = idx >> 6, dd = idx & 63;                 // i = k-dim, dd = out-dim
        int o = dd * WT_STRIDE + i;
        wt[0 * 64 * WT_STRIDE + o] = h16(Wq[idx]);
        wt[1 * 64 * WT_STRIDE + o] = h16(Wk[idx]);
        wt[2 * 64 * WT_STRIDE + o] = h16(Wf[idx]);
    }
    __syncthreads();

    // register-resident B fragments + bias
    half8 Bf[3][4][2];
    float bias[3][4];
    #pragma unroll
    for (int w = 0; w < 3; w++)
        #pragma unroll
        for (int nt = 0; nt < 4; nt++) {
            int n = nt * 16 + m;
            #pragma unroll
            for (int ks = 0; ks < 2; ks++)
                Bf[w][nt][ks] = *(const half8*)&wt[(w * 64 + n) * WT_STRIDE + ks * 32 + quad * 8];
        }
    #pragma unroll
    for (int nt = 0; nt < 4; nt++) {
        int n = nt * 16 + m;
        bias[0][nt] = bq[n]; bias[1][nt] = bk[n]; bias[2][nt] = bf[n];
    }

    const int NT  = N_NODES / 16;          // 6250 exact
    const int wid = pid * 4 + wave;

    for (int t = wid; t < NT; t += PROJ_WAVES) {
        int t0  = t * 16;
        int row = t0 + m;

        const floatx4* fr = (const floatx4*)(feat + (size_t)row * D + quad * 8);
        floatx4 x0 = __builtin_nontemporal_load(fr);
        floatx4 x1 = __builtin_nontemporal_load(fr + 1);
        floatx4 x2 = __builtin_nontemporal_load(fr + 8);
        floatx4 x3 = __builtin_nontemporal_load(fr + 9);

        half8 a0, a1;
        a0[0] = (_Float16)x0.x; a0[1] = (_Float16)x0.y;
        a0[2] = (_Float16)x0.z; a0[3] = (_Float16)x0.w;
        a0[4] = (_Float16)x1.x; a0[5] = (_Float16)x1.y;
        a0[6] = (_Float16)x1.z; a0[7] = (_Float16)x1.w;
        a1[0] = (_Float16)x2.x; a1[1] = (_Float16)x2.y;
        a1[2] = (_Float16)x2.z; a1[3] = (_Float16)x2.w;
        a1[4] = (_Float16)x3.x; a1[5] = (_Float16)x3.y;
        a1[6] = (_Float16)x3.z; a1[7] = (_Float16)x3.w;

        floatx4 acc[3][4];
        #pragma unroll
        for (int w = 0; w < 3; w++)
            #pragma unroll
            for (int nt = 0; nt < 4; nt++) {
                floatx4 c = {bias[w][nt], bias[w][nt], bias[w][nt], bias[w][nt]};
                c = __builtin_amdgcn_mfma_f32_16x16x32_f16(a0, Bf[w][nt][0], c, 0, 0, 0);
                c = __builtin_amdgcn_mfma_f32_16x16x32_f16(a1, Bf[w][nt][1], c, 0, 0, 0);
                acc[w][nt] = c;
            }

        // direct scalar stores (16-lane groups write 32B-contiguous chunks).
        // k and f interleaved into one 256B row: kf[node] = [k fp16 | f bf16]
        #pragma unroll
        for (int nt = 0; nt < 4; nt++) {
            int dim = nt * 16 + m;
            #pragma unroll
            for (int r = 0; r < 4; r++) {
                int node = t0 + quad * 4 + r;
                qh[(size_t)node * D + dim]        = h16(acc[0][nt][r]);
                kf[(size_t)node * 128 + dim]      = h16(acc[1][nt][r]);
                kf[(size_t)node * 128 + 64 + dim] = bfbits(acc[2][nt][r]);
            }
        }
    }
}

// ---- K2: build, one block (1024 thr) per bucket. Thread tid drains chunk
// tid's CONTIGUOUS run [o0,o1) for bucket b (runs come free from the scan).
// Slot ranks via LDS atomics over 391 counters; srcperm/counts writes dense
// and line-merged. Zero global atomics.
__global__ __launch_bounds__(1024) void build_k(
    const unsigned short* __restrict__ off16, const unsigned* __restrict__ pbuf,
    int* __restrict__ srcperm, int* __restrict__ counts) {

    const int b   = blockIdx.x;
    const int tid = threadIdx.x;

    __shared__ int cnt[BUCK_N];
    for (int i = tid; i < BUCK_N; i += 1024) cnt[i] = 0;
    __syncthreads();

    if (tid < PART_BLOCKS) {
        int o0 = off16[(size_t)tid * NBUCK + b];
        int o1;
        if (b < NBUCK - 1) {
            o1 = off16[(size_t)tid * NBUCK + b + 1];
        } else {
            o1 = N_EDGES - tid * CHUNK; if (o1 > CHUNK) o1 = CHUNK;
        }
        const unsigned* pp = pbuf + (size_t)tid * CHUNK;
        for (int r = o0; r < o1; r++) {
            unsigned p = pp[r];
            int loc = (int)(p & PK_MASK);
            int r2  = atomicAdd(&cnt[loc], 1);
            if (r2 < SLOTS)
                srcperm[(size_t)(b * BUCK_N + loc) * ROW + r2] =
                    (int)(p >> PK_SHIFT) << 8;       // kf byte offset = src*256
        }
    }
    __syncthreads();

    const int gbase = b * BUCK_N;
    for (int i = tid; i < BUCK_N; i += 1024) {
        int node = gbase + i;
        if (node < N_NODES) counts[node] = cnt[i];
    }
}

// ---- K3: VERBATIM R6-R9 (passing) node_agg: single-pass fused logits +
// exp + weighted aggregation, 2-deep pipeline, unconditional shuffles.
// Safety: logits ~ N(0,8); max over 1.6M edges ~ 43 << 88. Clamp at 85.
__global__ __launch_bounds__(256) void node_agg_k(
    const int* __restrict__ counts, const int* __restrict__ srcperm,
    const unsigned short* __restrict__ qh, const unsigned short* __restrict__ kf,
    float* __restrict__ out) {

    int wave = threadIdx.x >> 6;
    int lane = threadIdx.x & 63;
    int n    = blockIdx.x * 4 + wave;
    if (n >= N_NODES) return;

    const int l8 = lane & 7;      // dim group: dims l8*8 .. l8*8+7
    const int eg = lane >> 3;     // edge slot: 0..7

    // coalesced 256B slot-row hoist (slots >= deg are garbage; masked below)
    int offs_all = srcperm[(size_t)n * ROW + lane];
    uint4 uq = *(const uint4*)(qh + (size_t)n * D + l8 * 8);
    half2v qp0 = u2h(uq.x), qp1 = u2h(uq.y), qp2 = u2h(uq.z), qp3 = u2h(uq.w);

    int deg = counts[n];
    if (deg > SLOTS) deg = SLOTS;           // paranoia; never hit

    const char* kfb = (const char*)kf;

    float acc[8] = {0, 0, 0, 0, 0, 0, 0, 0};
    float l = 0.0f;   // 8x over-counted (all 8 l8-lanes add the same ez)

    // prologue: first 8-edge group's loads in flight (source lanes 0..7)
    bool v   = eg < deg;
    int  off = __shfl(offs_all, eg);
    off = v ? off : 0;
    uint4 ku = *(const uint4*)(kfb + off + l8 * 16);
    uint4 fu = *(const uint4*)(kfb + off + 128 + l8 * 16);

    for (int i0 = 0; i0 < deg; i0 += 8) {
        bool hasnext = (i0 + 8) < deg;       // wave-uniform
        int  i2  = i0 + 8 + eg;              // <= 63 always (i0 <= 48): valid lane
        bool v2  = i2 < deg;
        int  off2 = __shfl(offs_all, i2);    // unconditional: all lanes active
        off2 = v2 ? off2 : 0;
        uint4 kn = ku, fn = fu;
        if (hasnext) {
            kn = *(const uint4*)(kfb + off2 + l8 * 16);
            fn = *(const uint4*)(kfb + off2 + 128 + l8 * 16);
        }

        float dot = 0.0f;
        dot = fdot2(ku.x, qp0, dot);
        dot = fdot2(ku.y, qp1, dot);
        dot = fdot2(ku.z, qp2, dot);
        dot = fdot2(ku.w, qp3, dot);
        dot += __shfl_xor(dot, 1);
        dot += __shfl_xor(dot, 2);
        dot += __shfl_xor(dot, 4);          // all 8 lanes now hold the full dot

        float e  = dot > 0.0f ? dot : NEG_SLOPE * dot;
        e = fminf(e, 85.0f);
        float ez = v ? __expf(e) : 0.0f;
        l += ez;

        acc[0] = fmaf(ez, blo(fu.x), acc[0]);
        acc[1] = fmaf(ez, bhi(fu.x), acc[1]);
        acc[2] = fmaf(ez, blo(fu.y), acc[2]);
        acc[3] = fmaf(ez, bhi(fu.y), acc[3]);
        acc[4] = fmaf(ez, blo(fu.z), acc[4]);
        acc[5] = fmaf(ez, bhi(fu.z), acc[5]);
        acc[6] = fmaf(ez, blo(fu.w), acc[6]);
        acc[7] = fmaf(ez, bhi(fu.w), acc[7]);

        ku = kn; fu = fn; v = v2;
    }

    // reduce acc over the 8 edge slots (lanes differing in bits 3..5)
    #pragma unroll
    for (int d2 = 8; d2 < 64; d2 <<= 1) {
        #pragma unroll
        for (int j = 0; j < 8; j++) acc[j] += __shfl_xor(acc[j], d2);
    }
    // total l over all 64 lanes (8x the true denom -> inv = 8/l, exact scale)
    #pragma unroll
    for (int d2 = 1; d2 < 64; d2 <<= 1) l += __shfl_xor(l, d2);

    float inv = (deg > 0) ? 8.0f / fmaxf(l, 1e-30f) : 0.0f;
    if (eg == 0) {
        floatx4 o0 = {acc[0] * inv, acc[1] * inv, acc[2] * inv, acc[3] * inv};
        floatx4 o1 = {acc[4] * inv, acc[5] * inv, acc[6] * inv, acc[7] * inv};
        floatx4* op = (floatx4*)(out + (size_t)n * D + l8 * 8);
        __builtin_nontemporal_store(o0, op);
        __builtin_nontemporal_store(o1, op + 1);
    }
}

extern "C" void kernel_launch(void* const* d_in, const int* in_sizes, int n_in,
                              void* d_out, int out_size, void* d_ws, size_t ws_size,
                              hipStream_t stream) {
    const float* feat = (const float*)d_in[0];
    const int*   src  = (const int*)d_in[1];
    const int*   dst  = (const int*)d_in[2];
    const float* Wq   = (const float*)d_in[3];
    const float* bq   = (const float*)d_in[4];
    const float* Wk   = (const float*)d_in[5];
    const float* bk   = (const float*)d_in[6];
    const float* Wf   = (const float*)d_in[7];
    const float* bf   = (const float*)d_in[8];
    float* out = (float*)d_out;

    // workspace: qh(12.8MB) | kf(25.6MB) | srcperm(25.6MB, uninit; ROW=64) |
    //            counts(0.4MB, fully written by build_k) = 64.4MB
    //            (exact footprint proven by passing Rounds 6-9, 11).
    unsigned short* qh      = (unsigned short*)d_ws;
    unsigned short* kf      = qh + (size_t)N_NODES * D;
    int*            srcperm = (int*)(kf + (size_t)N_NODES * 2 * D);
    int*            counts  = srcperm + (size_t)N_NODES * ROW;

    // d_out scratch (25.6MB; only live between K1 and K2; node_agg_k fully
    // rewrites out afterwards -> re-entrant across graph replays):
    // pbuf 782*2048*4 = 6.41MB | off16 782*256*2 = 0.40MB
    unsigned*       pbuf  = (unsigned*)d_out;
    unsigned short* off16 = (unsigned short*)(pbuf + (size_t)PART_BLOCKS * CHUNK);

    // no memsets: all consumed state is fully rewritten every launch
    proj_part_k<<<FUSED_BLOCKS, 256, 0, stream>>>(
        feat, Wq, bq, Wk, bk, Wf, bf, qh, kf, src, dst, pbuf, off16);

    build_k<<<NBUCK, 1024, 0, stream>>>(off16, pbuf, srcperm, counts);

    node_agg_k<<<(N_NODES + 3) / 4, 256, 0, stream>>>(counts, srcperm, qh, kf, out);
}